// Round 4
// baseline (1268.963 us; speedup 1.0000x reference)
//
#include <hip/hip_runtime.h>
#include <stdint.h>

typedef __attribute__((ext_vector_type(8))) _Float16 half8;
typedef __attribute__((ext_vector_type(2))) _Float16 half2v;
typedef __attribute__((ext_vector_type(4))) float floatx4;
typedef __attribute__((ext_vector_type(4))) uint32_t uint4v;

#define KDIM 4096
#define NDIM 11008
#define BM 256
#define BN 256
#define BK 64
#define NKT (KDIM / BK)  // 64

static __device__ __forceinline__ uint32_t pkrtz(float a, float b) {
  // exact: staged values are fp16-representable, RTZ == RTN
  auto h = __builtin_amdgcn_cvt_pkrtz(a, b);
  return __builtin_bit_cast(uint32_t, h);
}

__global__ __launch_bounds__(512, 2)
void l4b_gemm(const float* __restrict__ X,   // fp16 widened to fp32 by harness
              const int* __restrict__ PW,
              const float* __restrict__ SC,  // fp16 widened to fp32
              float* __restrict__ OUT)       // fp32 out
{
  // Both tiles fp16, double buffered. Row = 64 halves = 128B = 8 x 16B slots.
  // Swizzle: phys_slot = s ^ (row & 7)  (balanced b128 reads/writes, 0 conflicts)
  __shared__ alignas(16) _Float16 la[2][BM * BK];  // 32KB x2
  __shared__ alignas(16) _Float16 lb[2][BN * BK];  // 32KB x2

  const int tid  = threadIdx.x;
  const int lane = tid & 63;
  const int wave = tid >> 6;

  // XCD-aware bijective swizzle (grid = 1376 = 8*172)
  const int nbx = NDIM / BN;  // 43
  const int cpx = (int)gridDim.x >> 3;
  const int wg  = (blockIdx.x & 7) * cpx + (blockIdx.x >> 3);
  const int by  = wg / nbx;
  const int bx  = wg - by * nbx;
  const int64_t brow = (int64_t)by * BM;
  const int     bcol = bx * BN;

  // 2M x 4N wave grid, wave tile 128x64
  const int wr = (wave >> 2) * 128;
  const int wc = (wave & 3) * 64;
  const int fr = lane & 15;
  const int fq = lane >> 4;

  floatx4 acc[8][4];
#pragma unroll
  for (int i = 0; i < 8; ++i)
#pragma unroll
    for (int j = 0; j < 4; ++j) acc[i][j] = (floatx4)(0.0f);

  // ---- A staging: thread -> (row = tid>>1, half = tid&1), 32 floats ----
  const int ar = tid >> 1;
  const int ah = tid & 1;
  const float* const aptr = X + (brow + ar) * (int64_t)KDIM + ah * 32;

  // ---- B staging: thread -> (col = tid&255, kq = tid>>8), 4 int32 ----
  const int bc  = tid & 255;
  const int bkq = tid >> 8;
  const int*   const pwcol = PW + bcol + bc;
  const float* const sccol = SC + bcol + bc;

  floatx4 ra[8];
  int     rw[4];
  float   rsc;

#define LOAD_A(t)                                                          \
  do {                                                                     \
    const float* ap = aptr + (t) * BK;                                     \
    _Pragma("unroll") for (int i_ = 0; i_ < 8; ++i_)                       \
        ra[i_] = *(const floatx4*)(ap + i_ * 4);                           \
  } while (0)

#define LOAD_B(t)                                                          \
  do {                                                                     \
    const int* pp = pwcol + ((t) * 8 + bkq) * NDIM;                        \
    _Pragma("unroll") for (int j_ = 0; j_ < 4; ++j_)                       \
        rw[j_] = pp[j_ * 2 * NDIM];                                        \
    rsc = sccol[(int64_t)((t) >> 1) * NDIM];                               \
  } while (0)

#define WRITE_A(dst)                                                       \
  do {                                                                     \
    _Pragma("unroll") for (int i2 = 0; i2 < 4; ++i2) {                     \
      uint4v u;                                                            \
      u[0] = pkrtz(ra[2 * i2][0], ra[2 * i2][1]);                          \
      u[1] = pkrtz(ra[2 * i2][2], ra[2 * i2][3]);                          \
      u[2] = pkrtz(ra[2 * i2 + 1][0], ra[2 * i2 + 1][1]);                  \
      u[3] = pkrtz(ra[2 * i2 + 1][2], ra[2 * i2 + 1][3]);                  \
      const int s_ = ah * 4 + i2;                                          \
      *(half8*)&(dst)[ar * BK + ((s_ ^ (ar & 7)) * 8)] =                   \
          __builtin_bit_cast(half8, u);                                    \
    }                                                                      \
  } while (0)

#define WRITE_B(dst)                                                       \
  do {                                                                     \
    const _Float16 ss = (_Float16)(rsc * (1.0f / 7.5f));                   \
    half2v ssv; ssv[0] = ss; ssv[1] = ss;                                  \
    half2v off; off[0] = (_Float16)(-1032.0f); off[1] = (_Float16)(-1032.0f); \
    _Pragma("unroll") for (int j_ = 0; j_ < 4; ++j_) {                     \
      const uint32_t q  = (uint32_t)rw[j_];                                \
      const uint32_t a0 = (q & 0x000F000Fu) | 0x64006400u;                 \
      const uint32_t a1 = ((q >> 4) & 0x000F000Fu) | 0x64006400u;          \
      const uint32_t a2 = ((q >> 8) & 0x000F000Fu) | 0x64006400u;          \
      const uint32_t a3 = ((q >> 12) & 0x000F000Fu) | 0x64006400u;         \
      const uint32_t p0 = __builtin_amdgcn_perm(a1, a0, 0x05040100u);      \
      const uint32_t p1 = __builtin_amdgcn_perm(a3, a2, 0x05040100u);      \
      const uint32_t p2 = __builtin_amdgcn_perm(a1, a0, 0x07060302u);      \
      const uint32_t p3 = __builtin_amdgcn_perm(a3, a2, 0x07060302u);      \
      uint4v u;                                                            \
      u[0] = __builtin_bit_cast(uint32_t, (__builtin_bit_cast(half2v, p0) + off) * ssv); \
      u[1] = __builtin_bit_cast(uint32_t, (__builtin_bit_cast(half2v, p1) + off) * ssv); \
      u[2] = __builtin_bit_cast(uint32_t, (__builtin_bit_cast(half2v, p2) + off) * ssv); \
      u[3] = __builtin_bit_cast(uint32_t, (__builtin_bit_cast(half2v, p3) + off) * ssv); \
      const int kp = bkq + 2 * j_;                                         \
      *(half8*)&(dst)[bc * BK + ((kp ^ (bc & 7)) * 8)] =                   \
          __builtin_bit_cast(half8, u);                                    \
    }                                                                      \
  } while (0)

#define READ_B4(ksl)                                                       \
  _Pragma("unroll") for (int fn_ = 0; fn_ < 4; ++fn_) {                    \
    const int n_ = wc + fn_ * 16 + fr;                                     \
    bfr[fn_] = *(const half8*)&lbp[n_ * BK + (((ksl) ^ (n_ & 7)) * 8)];    \
  }

#define READ_A4(fm0, ksl)                                                  \
  _Pragma("unroll") for (int fm_ = 0; fm_ < 4; ++fm_) {                    \
    const int m_ = wr + ((fm0) + fm_) * 16 + fr;                           \
    af[fm_] = *(const half8*)&lap[m_ * BK + (((ksl) ^ (m_ & 7)) * 8)];     \
  }

#define MFMA16(fm0)                                                        \
  __builtin_amdgcn_s_barrier();                                            \
  asm volatile("s_waitcnt lgkmcnt(0)" ::: "memory");                       \
  __builtin_amdgcn_sched_barrier(0);                                       \
  __builtin_amdgcn_s_setprio(1);                                           \
  _Pragma("unroll") for (int fm_ = 0; fm_ < 4; ++fm_)                      \
  _Pragma("unroll") for (int fn_ = 0; fn_ < 4; ++fn_)                      \
      acc[(fm0) + fm_][fn_] = __builtin_amdgcn_mfma_f32_16x16x32_f16(      \
          af[fm_], bfr[fn_], acc[(fm0) + fm_][fn_], 0, 0, 0);              \
  __builtin_amdgcn_s_setprio(0);                                           \
  __builtin_amdgcn_sched_barrier(0);                                       \
  __builtin_amdgcn_s_barrier();                                            \
  __builtin_amdgcn_sched_barrier(0);

  // ---- prologue: stage tile 0, put tile 1 loads in flight ----
  LOAD_A(0);
  LOAD_B(0);
  WRITE_A(la[0]);  // compiler-inserted vmcnt waits
  WRITE_B(lb[0]);
  LOAD_A(1);       // stay in flight across the barrier
  LOAD_B(1);
  asm volatile("s_waitcnt lgkmcnt(0)" ::: "memory");
  __builtin_amdgcn_s_barrier();
  __builtin_amdgcn_sched_barrier(0);

  for (int kt = 0; kt < NKT; ++kt) {
    const int buf = kt & 1;
    const _Float16* lap = la[buf];
    const _Float16* lbp = lb[buf];
    _Float16* const lan = la[buf ^ 1];
    _Float16* const lbn = lb[buf ^ 1];
    const bool haveW = (kt + 1 < NKT);  // stage tile kt+1 (regs already loaded)
    const bool haveL = (kt + 2 < NKT);  // issue loads for tile kt+2

    half8 bfr[4], af[4];

    // ---- P1: reads {B ks0, A fm0-3 ks0} | WRITE_A | MFMA q0 ----
    READ_B4(fq);
    READ_A4(0, fq);
    if (haveW) WRITE_A(lan);
    MFMA16(0);

    // ---- P2: reads {A fm4-7 ks0} | issue LOAD_A(kt+2) | MFMA q1 ----
    READ_A4(4, fq);
    if (haveL) LOAD_A(kt + 2);
    MFMA16(4);

    // ---- P3: reads {B ks1, A fm0-3 ks1} | WRITE_B | MFMA q2 ----
    READ_B4(4 + fq);
    READ_A4(0, 4 + fq);
    if (haveW) WRITE_B(lbn);
    MFMA16(0);

    // ---- P4: reads {A fm4-7 ks1} | issue LOAD_B(kt+2) | MFMA q3 ----
    READ_A4(4, 4 + fq);
    if (haveL) LOAD_B(kt + 2);
    MFMA16(4);
  }

  // ---- epilogue: C/D map col=lane&15, row=(lane>>4)*4+reg ----
#pragma unroll
  for (int fm = 0; fm < 8; ++fm)
#pragma unroll
    for (int fn = 0; fn < 4; ++fn)
#pragma unroll
      for (int r = 0; r < 4; ++r) {
        const int64_t row = brow + wr + fm * 16 + fq * 4 + r;
        const int     col = bcol + wc + fn * 16 + fr;
        OUT[row * NDIM + col] = acc[fm][fn][r];
      }
}

extern "C" void kernel_launch(void* const* d_in, const int* in_sizes, int n_in,
                              void* d_out, int out_size, void* d_ws, size_t ws_size,
                              hipStream_t stream) {
  const float* X   = (const float*)d_in[0];
  const int*   PW  = (const int*)d_in[1];
  const float* SC  = (const float*)d_in[2];
  float*       OUT = (float*)d_out;

  const int M    = in_sizes[0] / KDIM;      // 8192
  const int grid = (M / BM) * (NDIM / BN);  // 32 * 43 = 1376
  l4b_gemm<<<grid, 512, 0, stream>>>(X, PW, SC, OUT);
}